// Round 6
// baseline (630.387 us; speedup 1.0000x reference)
//
#include <hip/hip_runtime.h>

#define TT    512
#define HH    64
#define NB    2      // batches per block
#define NBLK  512    // 2 independent 4-wave blocks per CU -> stall overlap
#define HP    72     // h^T pitch in f16

typedef _Float16 f16x8 __attribute__((ext_vector_type(8)));
typedef _Float16 f16x4 __attribute__((ext_vector_type(4)));
typedef float    f32x4 __attribute__((ext_vector_type(4)));

__device__ __forceinline__ float sigmoidf_(float x) {
    return 1.0f / (1.0f + __expf(-x));
}
__device__ __forceinline__ float tanhf_(float x) {
    return 1.0f - 2.0f / (1.0f + __expf(2.0f * x));
}

// r15: r9's structure at half width -> 2 independent blocks per CU.
// 512 blocks x 256 threads (4 waves). Block owns NB=2 batches (cols 0..1).
// Group A = waves 0-1 (layer 1), group C = waves 2-3 (layer 2, fused K=128
// over [h1; h2]). Wave w of a group owns 8 M-tiles tau = w + 2*g8: rows
// 16w+32*g8+[0..15] = (gate g8>>1, units 16w+32*(g8&1)+[0..15]).
// Cell transpose -> 1 cell/lane pointwise on all 64 lanes (r10 lesson).
// One barrier per tick (now 4-wave rendezvous); the CU's second block runs
// the same loop phase-INDEPENDENTLY -> its waves fill this block's LDS/
// barrier stalls (r12 lesson: 512t blocks can't co-reside, 96 VGPR + ~64
// AGPR ~ 160 regs -> 3 waves/SIMD max; 256t blocks at <=256 regs fit 2+2).
// Per-row arithmetic bitwise identical to r9/r14 (A: 3-chain MFMA, C:
// split 2+2 chain validated in r10/r14) -> same absmax class.
// LESSONS: r8 cross-block handoff 4x; r10 pointwise on 16 lanes 2x; r13
// 2-wave/128t issue-bound 2.2x. Keep the thin-per-wave 1-barrier shape.
__global__ __launch_bounds__(256, 2) void lstm_mfma(
    const float* __restrict__ x,
    const float* __restrict__ w_ih0, const float* __restrict__ w_hh0,
    const float* __restrict__ b_ih0, const float* __restrict__ b_hh0,
    const float* __restrict__ w_ih1, const float* __restrict__ w_hh1,
    const float* __restrict__ b_ih1, const float* __restrict__ b_hh1,
    const float* __restrict__ w_out, const float* __restrict__ b_out,
    float* __restrict__ out)
{
    __shared__ __align__(16) _Float16 h1T[2][16 * HP];  // h1^T [batch][unit] f16
    __shared__ __align__(16) _Float16 h2T[2][16 * HP];  // h2^T
    __shared__ float xs[TT * 12];                       // x [t][d][4] fp32 (r9 layout)
    __shared__ __align__(16) f32x4 cellA[2][72];        // A gate transpose (pad stride 9)
    __shared__ __align__(16) f32x4 cellC[2][72];        // C gate transpose
    __shared__ float h2f[2][68];                        // final h2 fp32
    __shared__ float lg[2][4];

    const int tid   = threadIdx.x;
    const int group = tid >> 7;          // 0 = A (layer 1), 1 = C (layer 2)
    const int w     = (tid >> 6) & 1;    // wave-in-group
    const int lane  = tid & 63;
    const int quad  = lane >> 4;
    const int n     = lane & 15;         // MFMA column = batch slot
    const int b0    = blockIdx.x * NB;

    // transposed-cell mapping: lane -> (unit-in-wave up=lane>>1, batch cb2=lane&1)
    const int up    = lane >> 1;
    const int cb2   = lane & 1;
    const int unit  = 32 * (up >> 4) + 16 * w + (up & 15);  // global unit 0..63
    const int rdphys = lane + (lane >> 3);                  // padded cell slot

    // ---- persistent weight fragments ----
    // A: whh = W_hh0 frags (K=64), wih[g8][0] holds the K=3 x-transform.
    // C: wih = W_ih1, whh = W_hh1.
    f16x8 whh[8][2], wih[8][2];
    f32x4 biasf[8];
    #pragma unroll
    for (int g8 = 0; g8 < 8; ++g8) {
        const int arow = 16 * w + 32 * g8 + n;        // A-frag row m = lane&15
        const float* ph = (group == 0) ? (w_hh0 + arow * HH) : (w_hh1 + arow * HH);
        const float* pi = w_ih1 + arow * HH;
        #pragma unroll
        for (int k0 = 0; k0 < 2; ++k0) {
            #pragma unroll
            for (int j = 0; j < 8; ++j) {
                whh[g8][k0][j] = (_Float16)ph[quad * 8 + 32 * k0 + j];
                wih[g8][k0][j] = (group == 1) ? (_Float16)pi[quad * 8 + 32 * k0 + j]
                                              : (_Float16)0.f;
            }
        }
        #pragma unroll
        for (int r = 0; r < 4; ++r) {                 // C/D row = quad*4 + r
            const int crow = 16 * w + 32 * g8 + quad * 4 + r;
            biasf[g8][r] = (group == 0) ? (b_ih0[crow] + b_hh0[crow])
                                        : (b_ih1[crow] + b_hh1[crow]);
        }
        if (group == 0) {                             // K=3 x-transform into wih[g8][0]
            f16x8 ax;
            #pragma unroll
            for (int j = 0; j < 8; ++j) ax[j] = (_Float16)0.f;
            if (quad == 0) {
                ax[0] = (_Float16)w_ih0[arow * 3 + 0];
                ax[1] = (_Float16)w_ih0[arow * 3 + 1];
                ax[2] = (_Float16)w_ih0[arow * 3 + 2];
            }
            wih[g8][0] = ax;
        }
    }

    // ---- LDS init ----
    for (int i = tid; i < 2 * 16 * HP; i += 256) {
        ((_Float16*)h1T)[i] = (_Float16)0.f;
        ((_Float16*)h2T)[i] = (_Float16)0.f;
    }
    for (int i = tid; i < TT * 12; i += 256) {
        const int t = i / 12, rem = i - t * 12;
        const int d = rem >> 2, b = rem & 3;          // only slots b<NB real
        xs[i] = (b < NB) ? x[(size_t)(b0 + b) * (TT * 3) + t * 3 + d] : 0.f;
    }
    __syncthreads();

    float creg = 0.f;    // A: c1 of (unit, cb2); C: c2 of same

    for (int t = 0; t <= TT; ++t) {
        if (group == 0) {
            if (t < TT) {
                f16x8 bx;
                #pragma unroll
                for (int j = 0; j < 8; ++j) bx[j] = (_Float16)0.f;
                if (quad == 0) {
                    const float* xp = xs + t * 12 + (lane & 3);
                    bx[0] = (_Float16)xp[0];
                    bx[1] = (_Float16)xp[4];
                    bx[2] = (_Float16)xp[8];
                }
                const _Float16* hsrc = h1T[(t + 1) & 1];
                const f16x8 bh0 = *(const f16x8*)(hsrc + n * HP + quad * 8);
                const f16x8 bh1 = *(const f16x8*)(hsrc + n * HP + quad * 8 + 32);
                f32x4 acc[8];
                #pragma unroll
                for (int g8 = 0; g8 < 8; ++g8) {
                    f32x4 a = __builtin_amdgcn_mfma_f32_16x16x32_f16(wih[g8][0], bx, biasf[g8], 0, 0, 0);
                    a = __builtin_amdgcn_mfma_f32_16x16x32_f16(whh[g8][0], bh0, a, 0, 0, 0);
                    a = __builtin_amdgcn_mfma_f32_16x16x32_f16(whh[g8][1], bh1, a, 0, 0, 0);
                    acc[g8] = a;
                }
                if (n < 2) {
                    #pragma unroll
                    for (int h = 0; h < 2; ++h) {
                        #pragma unroll
                        for (int r = 0; r < 4; ++r) {
                            const int slot = 32 * h + 8 * quad + 2 * r + n;
                            f32x4 v = {acc[h][r], acc[2 + h][r], acc[4 + h][r], acc[6 + h][r]};
                            cellA[w][slot + (slot >> 3)] = v;
                        }
                    }
                }
                const f32x4 gate = cellA[w][rdphys];
                const float is = sigmoidf_(gate[0]);
                const float fs = sigmoidf_(gate[1]);
                const float gt = tanhf_(gate[2]);
                const float os = sigmoidf_(gate[3]);
                creg = fs * creg + is * gt;
                h1T[t & 1][cb2 * HP + unit] = (_Float16)(os * tanhf_(creg));
            }
        } else {
            if (t >= 1) {
                // fused K=128 matvec over [h1(t-1); h2(t-2)], split 2+2 chains
                const _Float16* h1src = h1T[(t + 1) & 1];
                const _Float16* h2src = h2T[(t + 1) & 1];
                const f16x8 b10 = *(const f16x8*)(h1src + n * HP + quad * 8);
                const f16x8 b11 = *(const f16x8*)(h1src + n * HP + quad * 8 + 32);
                const f16x8 b20 = *(const f16x8*)(h2src + n * HP + quad * 8);
                const f16x8 b21 = *(const f16x8*)(h2src + n * HP + quad * 8 + 32);
                const f32x4 zero4 = {0.f, 0.f, 0.f, 0.f};
                f32x4 acc[8];
                #pragma unroll
                for (int g8 = 0; g8 < 8; ++g8) {
                    f32x4 p = __builtin_amdgcn_mfma_f32_16x16x32_f16(wih[g8][0], b10, biasf[g8], 0, 0, 0);
                    p = __builtin_amdgcn_mfma_f32_16x16x32_f16(wih[g8][1], b11, p, 0, 0, 0);
                    f32x4 q4 = __builtin_amdgcn_mfma_f32_16x16x32_f16(whh[g8][0], b20, zero4, 0, 0, 0);
                    q4 = __builtin_amdgcn_mfma_f32_16x16x32_f16(whh[g8][1], b21, q4, 0, 0, 0);
                    acc[g8] = p + q4;
                }
                if (n < 2) {
                    #pragma unroll
                    for (int h = 0; h < 2; ++h) {
                        #pragma unroll
                        for (int r = 0; r < 4; ++r) {
                            const int slot = 32 * h + 8 * quad + 2 * r + n;
                            f32x4 v = {acc[h][r], acc[2 + h][r], acc[4 + h][r], acc[6 + h][r]};
                            cellC[w][slot + (slot >> 3)] = v;
                        }
                    }
                }
                const f32x4 gate = cellC[w][rdphys];
                const float is = sigmoidf_(gate[0]);
                const float fs = sigmoidf_(gate[1]);
                const float gt = tanhf_(gate[2]);
                const float os = sigmoidf_(gate[3]);
                creg = fs * creg + is * gt;
                const float h = os * tanhf_(creg);
                h2T[t & 1][cb2 * HP + unit] = (_Float16)h;   // h2(t-1)
                if (t == TT) h2f[cb2][unit] = h;             // h2(TT-1) fp32
            }
        }
        __syncthreads();
    }

    // ---- epilogue: logits + softmax on fp32 h2 ----
    if (tid < 8) {
        const int b = tid & 1, o = tid >> 1;
        float acc = b_out[o];
        #pragma unroll
        for (int j = 0; j < HH; ++j)
            acc = fmaf(w_out[o * HH + j], h2f[b][j], acc);
        lg[b][o] = acc;
    }
    __syncthreads();
    if (tid < NB) {
        const int b = tid;
        const float l0 = lg[b][0], l1 = lg[b][1], l2 = lg[b][2], l3 = lg[b][3];
        const float m  = fmaxf(fmaxf(l0, l1), fmaxf(l2, l3));
        const float e0 = __expf(l0 - m), e1 = __expf(l1 - m);
        const float e2 = __expf(l2 - m), e3 = __expf(l3 - m);
        const float sum = 1.0f / (e0 + e1 + e2 + e3);
        out[(b0 + b) * 4 + 0] = e0 * sum;
        out[(b0 + b) * 4 + 1] = e1 * sum;
        out[(b0 + b) * 4 + 2] = e2 * sum;
        out[(b0 + b) * 4 + 3] = e3 * sum;
    }
}

extern "C" void kernel_launch(void* const* d_in, const int* in_sizes, int n_in,
                              void* d_out, int out_size, void* d_ws, size_t ws_size,
                              hipStream_t stream) {
    const float* x     = (const float*)d_in[0];
    const float* w_ih0 = (const float*)d_in[1];
    const float* w_hh0 = (const float*)d_in[2];
    const float* b_ih0 = (const float*)d_in[3];
    const float* b_hh0 = (const float*)d_in[4];
    const float* w_ih1 = (const float*)d_in[5];
    const float* w_hh1 = (const float*)d_in[6];
    const float* b_ih1 = (const float*)d_in[7];
    const float* b_hh1 = (const float*)d_in[8];
    const float* w_out = (const float*)d_in[9];
    const float* b_out = (const float*)d_in[10];
    float* out = (float*)d_out;

    hipLaunchKernelGGL(lstm_mfma, dim3(NBLK), dim3(256), 0, stream,
                       x, w_ih0, w_hh0, b_ih0, b_hh0,
                       w_ih1, w_hh1, b_ih1, b_hh1,
                       w_out, b_out, out);
}

// Round 7
// 524.774 us; speedup vs baseline: 1.2013x; 1.2013x over previous
//
#include <hip/hip_runtime.h>

#define TT    512
#define HH    64
#define NB    4
#define NBLK  256
#define HP    72    // h^T pitch in f16

typedef _Float16 f16x8 __attribute__((ext_vector_type(8)));
typedef _Float16 f16x4 __attribute__((ext_vector_type(4)));
typedef float    f32x4 __attribute__((ext_vector_type(4)));

__device__ __forceinline__ float sigmoidf_(float x) {
    return 1.0f / (1.0f + __expf(-x));
}
__device__ __forceinline__ float tanhf_(float x) {
    return 1.0f - 2.0f / (1.0f + __expf(2.0f * x));
}

__device__ __forceinline__ void spin_ge(int* p, int target) {
    while (__hip_atomic_load(p, __ATOMIC_ACQUIRE, __HIP_MEMORY_SCOPE_WORKGROUP)
           < target) {}
}

// r16 = r9's 8-thin-wave geometry with the block-wide barrier DELETED.
// 256 blocks x 512 threads. Group A = waves 0-3 (layer 1), group C = waves
// 4-7 (layer 2, fused K=128 over [h1; h2]). Wave w owns M-tiles
// {w,w+4,w+8,w+12}; cell transpose -> 1 cell/lane pointwise on all 64 lanes.
// Phase-decoupling (NEW): A and C no longer rendezvous per tick. Per-group
// software barriers via monotonic LDS counters (lane0 release-add, all-lane
// acquire-spin — mechanism proven correct in r13), and the h1 hop deepened
// to a 4-slot ring so A can run up to 3 ticks ahead of C. Each SIMD then
// hosts one A-wave and one C-wave at DIFFERENT phases -> one wave's LDS/MFMA
// stalls are filled by the other's issue (r15 showed wave overlap raises
// MfmaUtil; r15 lost on fat waves + spill. Here waves stay thin, regs = r9).
// Protocol (ctrA/ctrC count completed wave-ticks, 4 per group-tick):
//   A tick t (0..TT-1): need ctrA>=4t (own group t-1 done);
//                       need ctrC>=4(t-3) (ring slot t&3 consumed);
//     read h1T[(t-1)&3] -> write h1T[t&3]; then ctrA += 1 (release).
//   C tick t (1..TT):   need ctrC>=4(t-1); need ctrA>=4t (h1(t-1) ready);
//     read h1T[(t-1)&3], h2T[(t+1)&1] -> write h2T[t&1]; ctrC += 1.
// Arithmetic: layer 1 bitwise identical to r9; layer 2 split 2+2 chains
// (validated r10/r15, absmax 9.8e-4).
// LESSONS: r8 cross-block handoff 4x; r10 pointwise on 16 lanes 2x; r12
// 512t blocks never co-reside (reg granule); r13 2 fat waves issue-bound;
// r14 MFMA-latency cuts neutral; r15 fat waves + spill.
__global__ __launch_bounds__(512) void lstm_mfma(
    const float* __restrict__ x,
    const float* __restrict__ w_ih0, const float* __restrict__ w_hh0,
    const float* __restrict__ b_ih0, const float* __restrict__ b_hh0,
    const float* __restrict__ w_ih1, const float* __restrict__ w_hh1,
    const float* __restrict__ b_ih1, const float* __restrict__ b_hh1,
    const float* __restrict__ w_out, const float* __restrict__ b_out,
    float* __restrict__ out)
{
    __shared__ __align__(16) _Float16 h1T[4][16 * HP];  // h1 ring, depth 4
    __shared__ __align__(16) _Float16 h2T[2][16 * HP];  // h2 hop (C private)
    __shared__ float xs[TT * 12];                       // x [t][d][4] fp32
    __shared__ __align__(16) f32x4 cellA[4][64];        // A gate transpose
    __shared__ __align__(16) f32x4 cellC[4][64];        // C gate transpose
    __shared__ __align__(16) float h2f[16 * 68];        // final h2 fp32
    __shared__ float lg[NB][4];
    __shared__ int ctrA, ctrC;                          // completed wave-ticks

    const int tid   = threadIdx.x;
    const int group = tid >> 8;          // 0 = A (layer 1), 1 = C (layer 2)
    const int w     = (tid >> 6) & 3;    // wave-in-group
    const int lane  = tid & 63;
    const int quad  = lane >> 4;
    const int n     = lane & 15;         // MFMA column = batch slot
    const int b0    = blockIdx.x * NB;

    const int cu    = lane >> 2;                      // unit after transpose
    const int cb    = lane & 3;                       // batch after transpose
    const int rdslot = lane ^ ((lane >> 4) << 2);     // XOR-swizzled cell slot

    // ---- persistent weight fragments ----
    f16x8 whh[4][2], wih[4][2], axf[4];
    f32x4 biasf[4];
    #pragma unroll
    for (int g_ = 0; g_ < 4; ++g_) {
        const int arow = 16 * w + 64 * g_ + n;        // A-frag row m = lane&15
        const float* ph = (group == 0) ? (w_hh0 + arow * HH) : (w_hh1 + arow * HH);
        const float* pi = w_ih1 + arow * HH;
        #pragma unroll
        for (int k0 = 0; k0 < 2; ++k0) {
            #pragma unroll
            for (int j = 0; j < 8; ++j) {
                whh[g_][k0][j] = (_Float16)ph[quad * 8 + 32 * k0 + j];
                wih[g_][k0][j] = (group == 1) ? (_Float16)pi[quad * 8 + 32 * k0 + j]
                                              : (_Float16)0.f;
            }
        }
        #pragma unroll
        for (int r = 0; r < 4; ++r) {                 // C/D row = quad*4 + r
            const int crow = 16 * w + 64 * g_ + quad * 4 + r;
            biasf[g_][r] = (group == 0) ? (b_ih0[crow] + b_hh0[crow])
                                        : (b_ih1[crow] + b_hh1[crow]);
        }
        f16x8 ax;
        #pragma unroll
        for (int j = 0; j < 8; ++j) ax[j] = (_Float16)0.f;
        if (group == 0 && quad == 0) {                // K=3 x-transform
            ax[0] = (_Float16)w_ih0[arow * 3 + 0];
            ax[1] = (_Float16)w_ih0[arow * 3 + 1];
            ax[2] = (_Float16)w_ih0[arow * 3 + 2];
        }
        axf[g_] = ax;
    }

    // ---- LDS init ----
    for (int i = tid; i < 2304; i += 512) ((int*)h1T)[i] = 0;   // 4 slots
    for (int i = tid; i < 1152; i += 512) ((int*)h2T)[i] = 0;   // 2 slots
    for (int i = tid; i < TT * 12; i += 512) {
        const int t = i / 12, rem = i - t * 12;
        const int d = rem >> 2, b = rem & 3;
        xs[i] = x[(size_t)(b0 + b) * (TT * 3) + t * 3 + d];
    }
    if (tid == 0) { ctrA = 0; ctrC = 0; }
    __syncthreads();

    float creg = 0.f;    // A: c1 of (unit 16w+cu, batch cb); C: c2 of same

    if (group == 0) {
        // ===================== group A : layer 1 =====================
        for (int t = 0; t < TT; ++t) {
            if (t >= 1) spin_ge(&ctrA, 4 * t);            // own group t-1 done
            if (t >= 4) spin_ge(&ctrC, 4 * (t - 3));      // ring slot consumed
            f16x8 bx;
            #pragma unroll
            for (int j = 0; j < 8; ++j) bx[j] = (_Float16)0.f;
            if (quad == 0) {
                const float* xp = xs + t * 12 + (lane & 3);
                bx[0] = (_Float16)xp[0];
                bx[1] = (_Float16)xp[4];
                bx[2] = (_Float16)xp[8];
            }
            const _Float16* hsrc = h1T[(t - 1) & 3];      // h1(t-1); t=0 -> slot3 zeros
            const f16x8 bh0 = *(const f16x8*)(hsrc + n * HP + quad * 8);
            const f16x8 bh1 = *(const f16x8*)(hsrc + n * HP + quad * 8 + 32);
            f32x4 acc[4];
            #pragma unroll
            for (int g_ = 0; g_ < 4; ++g_) {
                f32x4 a = __builtin_amdgcn_mfma_f32_16x16x32_f16(axf[g_], bx, biasf[g_], 0, 0, 0);
                a = __builtin_amdgcn_mfma_f32_16x16x32_f16(whh[g_][0], bh0, a, 0, 0, 0);
                a = __builtin_amdgcn_mfma_f32_16x16x32_f16(whh[g_][1], bh1, a, 0, 0, 0);
                acc[g_] = a;
            }
            if (n < 4) {
                #pragma unroll
                for (int r = 0; r < 4; ++r) {
                    const int slot = (16 * quad + 4 * r + n) ^ (quad << 2);
                    f32x4 v = {acc[0][r], acc[1][r], acc[2][r], acc[3][r]};
                    cellA[w][slot] = v;
                }
            }
            const f32x4 gate = cellA[w][rdslot];
            const float is = sigmoidf_(gate[0]);
            const float fs = sigmoidf_(gate[1]);
            const float gt = tanhf_(gate[2]);
            const float os = sigmoidf_(gate[3]);
            creg = fs * creg + is * gt;
            h1T[t & 3][cb * HP + 16 * w + cu] = (_Float16)(os * tanhf_(creg));
            if (lane == 0)
                __hip_atomic_fetch_add(&ctrA, 1, __ATOMIC_RELEASE,
                                       __HIP_MEMORY_SCOPE_WORKGROUP);
        }
    } else {
        // ===================== group C : layer 2 =====================
        for (int t = 1; t <= TT; ++t) {
            if (t >= 2) spin_ge(&ctrC, 4 * (t - 1));      // own group t-1 done
            spin_ge(&ctrA, 4 * t);                        // h1(t-1) published
            const _Float16* h1src = h1T[(t - 1) & 3];     // h1(t-1)
            const _Float16* h2src = h2T[(t + 1) & 1];     // h2(t-2), own write
            const f16x8 b10 = *(const f16x8*)(h1src + n * HP + quad * 8);
            const f16x8 b11 = *(const f16x8*)(h1src + n * HP + quad * 8 + 32);
            const f16x8 b20 = *(const f16x8*)(h2src + n * HP + quad * 8);
            const f16x8 b21 = *(const f16x8*)(h2src + n * HP + quad * 8 + 32);
            const f32x4 zero4 = {0.f, 0.f, 0.f, 0.f};
            f32x4 acc[4];
            #pragma unroll
            for (int g_ = 0; g_ < 4; ++g_) {
                f32x4 p = __builtin_amdgcn_mfma_f32_16x16x32_f16(wih[g_][0], b10, biasf[g_], 0, 0, 0);
                p = __builtin_amdgcn_mfma_f32_16x16x32_f16(wih[g_][1], b11, p, 0, 0, 0);
                f32x4 q4 = __builtin_amdgcn_mfma_f32_16x16x32_f16(whh[g_][0], b20, zero4, 0, 0, 0);
                q4 = __builtin_amdgcn_mfma_f32_16x16x32_f16(whh[g_][1], b21, q4, 0, 0, 0);
                acc[g_] = p + q4;
            }
            if (n < 4) {
                #pragma unroll
                for (int r = 0; r < 4; ++r) {
                    const int slot = (16 * quad + 4 * r + n) ^ (quad << 2);
                    f32x4 v = {acc[0][r], acc[1][r], acc[2][r], acc[3][r]};
                    cellC[w][slot] = v;
                }
            }
            const f32x4 gate = cellC[w][rdslot];
            const float is = sigmoidf_(gate[0]);
            const float fs = sigmoidf_(gate[1]);
            const float gt = tanhf_(gate[2]);
            const float os = sigmoidf_(gate[3]);
            creg = fs * creg + is * gt;
            const float h = os * tanhf_(creg);
            h2T[t & 1][cb * HP + 16 * w + cu] = (_Float16)h;   // h2(t-1)
            if (t == TT) h2f[cb * 68 + 16 * w + cu] = h;       // h2(TT-1) fp32
            if (lane == 0)
                __hip_atomic_fetch_add(&ctrC, 1, __ATOMIC_RELEASE,
                                       __HIP_MEMORY_SCOPE_WORKGROUP);
        }
    }
    __syncthreads();

    // ---- epilogue: logits + softmax on fp32 h2 ----
    if (tid < 16) {
        const int b = tid & 3, o = tid >> 2;
        float acc = b_out[o];
        #pragma unroll
        for (int j = 0; j < HH; ++j)
            acc = fmaf(w_out[o * HH + j], h2f[b * 68 + j], acc);
        lg[b][o] = acc;
    }
    __syncthreads();
    if (tid < NB) {
        const int b = tid;
        const float l0 = lg[b][0], l1 = lg[b][1], l2 = lg[b][2], l3 = lg[b][3];
        const float m  = fmaxf(fmaxf(l0, l1), fmaxf(l2, l3));
        const float e0 = __expf(l0 - m), e1 = __expf(l1 - m);
        const float e2 = __expf(l2 - m), e3 = __expf(l3 - m);
        const float sum = 1.0f / (e0 + e1 + e2 + e3);
        out[(b0 + b) * 4 + 0] = e0 * sum;
        out[(b0 + b) * 4 + 1] = e1 * sum;
        out[(b0 + b) * 4 + 2] = e2 * sum;
        out[(b0 + b) * 4 + 3] = e3 * sum;
    }
}

extern "C" void kernel_launch(void* const* d_in, const int* in_sizes, int n_in,
                              void* d_out, int out_size, void* d_ws, size_t ws_size,
                              hipStream_t stream) {
    const float* x     = (const float*)d_in[0];
    const float* w_ih0 = (const float*)d_in[1];
    const float* w_hh0 = (const float*)d_in[2];
    const float* b_ih0 = (const float*)d_in[3];
    const float* b_hh0 = (const float*)d_in[4];
    const float* w_ih1 = (const float*)d_in[5];
    const float* w_hh1 = (const float*)d_in[6];
    const float* b_ih1 = (const float*)d_in[7];
    const float* b_hh1 = (const float*)d_in[8];
    const float* w_out = (const float*)d_in[9];
    const float* b_out = (const float*)d_in[10];
    float* out = (float*)d_out;

    hipLaunchKernelGGL(lstm_mfma, dim3(NBLK), dim3(512), 0, stream,
                       x, w_ih0, w_hh0, b_ih0, b_hh0,
                       w_ih1, w_hh1, b_ih1, b_hh1,
                       w_out, b_out, out);
}

// Round 8
// 409.089 us; speedup vs baseline: 1.5410x; 1.2828x over previous
//
#include <hip/hip_runtime.h>

#define TT    512
#define HH    64
#define NB    4
#define NBLK  256
#define HP    72    // h^T pitch in f16

typedef _Float16 f16x8 __attribute__((ext_vector_type(8)));
typedef _Float16 f16x4 __attribute__((ext_vector_type(4)));
typedef float    f32x4 __attribute__((ext_vector_type(4)));

// r17: fast pointwise. Without -ffast-math, 1.0f/x compiles to the full IEEE
// div sequence (~8-10 inst); x5 divides per gate-set this is ~320 cy of VALU
// issue per set (measured via r10's unintended ablation: +3 sets/wave ->
// +383us, VALU-time 230->648us). v_rcp_f32 is 1 inst, ~1ulp — noise vs the
// 3.9e-3 f16-dominated error. Saturation is graceful: exp->inf => rcp->0.
__device__ __forceinline__ float sigmoidf_(float x) {
    return __builtin_amdgcn_rcpf(1.0f + __expf(-x));
}
__device__ __forceinline__ float tanhf_(float x) {
    return 1.0f - 2.0f * __builtin_amdgcn_rcpf(1.0f + __expf(2.0f * x));
}

// Body = r9 (the proven 460us kernel) verbatim; ONLY sigmoidf_/tanhf_ above
// changed (v_rcp instead of IEEE divide).
// 256 blocks x 512 threads (8 waves). Block owns 4 batches (cols 0..3 of the
// 16-col MFMA tile). Group A = waves 0-3 (layer 1), group C = waves 4-7
// (layer 2, FUSED K=128 matvec over [h1; h2]).
// Wave w of a group owns M-tiles {w,w+4,w+8,w+12} (i,f,g,o of units
// [16w,16w+16) in one lane's accumulators); cell transpose -> 1 cell/lane
// pointwise. One barrier per tick, ticks 0..TT:
//   A (t<TT): g1(t) = b1 + W_ih0 x(t) + W_hh0 h1(t-1) -> h1(t) -> h1T[t&1]
//   C (t>=1): g2 = b2 + W_ih1 h1(t-1) + W_hh1 h2(t-2)  -> h2(t-1) -> h2T[t&1]
// LESSONS: r8 cross-block handoff 4x. r10 pointwise concentrated on 16
// lanes (4 sets/wave) 2x — pointwise VALU issue is a first-order term.
// r12 512t blocks never co-reside (reg granule). r13 fat 2-wave 2.2x.
// r14 MFMA-latency cuts neutral. r15 fat waves + spill. r16 software
// spin-barriers 10% worse than s_barrier.
__global__ __launch_bounds__(512) void lstm_mfma(
    const float* __restrict__ x,
    const float* __restrict__ w_ih0, const float* __restrict__ w_hh0,
    const float* __restrict__ b_ih0, const float* __restrict__ b_hh0,
    const float* __restrict__ w_ih1, const float* __restrict__ w_hh1,
    const float* __restrict__ b_ih1, const float* __restrict__ b_hh1,
    const float* __restrict__ w_out, const float* __restrict__ b_out,
    float* __restrict__ out)
{
    __shared__ __align__(16) _Float16 h1T[2][16 * HP];  // h1^T [batch][unit] f16
    __shared__ __align__(16) _Float16 h2T[2][16 * HP];  // h2^T
    __shared__ float xs[TT * 12];                       // x [t][d][4] fp32
    __shared__ __align__(16) f32x4 cellA[4][64];        // A gate transpose
    __shared__ __align__(16) f32x4 cellC[4][64];        // C gate transpose
    __shared__ __align__(16) float h2f[16 * 68];        // final h2 fp32
    __shared__ float lg[NB][4];

    const int tid   = threadIdx.x;
    const int group = tid >> 8;          // 0 = A (layer 1), 1 = C (layer 2)
    const int w     = (tid >> 6) & 3;    // wave-in-group
    const int lane  = tid & 63;
    const int quad  = lane >> 4;
    const int n     = lane & 15;         // MFMA column = batch slot
    const int b0    = blockIdx.x * NB;

    const int cu    = lane >> 2;                      // unit after transpose
    const int cb    = lane & 3;                       // batch after transpose
    const int rdslot = lane ^ ((lane >> 4) << 2);     // XOR-swizzled cell slot

    // ---- persistent weight fragments ----
    // A: whh = W_hh0 frags (K=64), axf = x transform;  C: wih = W_ih1, whh = W_hh1
    f16x8 whh[4][2], wih[4][2], axf[4];
    f32x4 biasf[4];
    #pragma unroll
    for (int g_ = 0; g_ < 4; ++g_) {
        const int arow = 16 * w + 64 * g_ + n;        // A-frag row m = lane&15
        const float* ph = (group == 0) ? (w_hh0 + arow * HH) : (w_hh1 + arow * HH);
        const float* pi = w_ih1 + arow * HH;
        #pragma unroll
        for (int k0 = 0; k0 < 2; ++k0) {
            #pragma unroll
            for (int j = 0; j < 8; ++j) {
                whh[g_][k0][j] = (_Float16)ph[quad * 8 + 32 * k0 + j];
                wih[g_][k0][j] = (group == 1) ? (_Float16)pi[quad * 8 + 32 * k0 + j]
                                              : (_Float16)0.f;
            }
        }
        #pragma unroll
        for (int r = 0; r < 4; ++r) {                 // C/D row = quad*4 + r
            const int crow = 16 * w + 64 * g_ + quad * 4 + r;
            biasf[g_][r] = (group == 0) ? (b_ih0[crow] + b_hh0[crow])
                                        : (b_ih1[crow] + b_hh1[crow]);
        }
        f16x8 ax;
        #pragma unroll
        for (int j = 0; j < 8; ++j) ax[j] = (_Float16)0.f;
        if (group == 0 && quad == 0) {                // K=3 x-transform
            ax[0] = (_Float16)w_ih0[arow * 3 + 0];
            ax[1] = (_Float16)w_ih0[arow * 3 + 1];
            ax[2] = (_Float16)w_ih0[arow * 3 + 2];
        }
        axf[g_] = ax;
    }

    // ---- LDS init ----
    for (int i = tid; i < 1152; i += 512) {
        ((int*)h1T)[i] = 0;
        ((int*)h2T)[i] = 0;
    }
    for (int i = tid; i < TT * 12; i += 512) {
        const int t = i / 12, rem = i - t * 12;
        const int d = rem >> 2, b = rem & 3;
        xs[i] = x[(size_t)(b0 + b) * (TT * 3) + t * 3 + d];
    }
    __syncthreads();

    float creg = 0.f;    // A: c1 of (unit 16w+cu, batch cb); C: c2 of same

    for (int t = 0; t <= TT; ++t) {
        if (group == 0) {
            if (t < TT) {
                f16x8 bx;
                #pragma unroll
                for (int j = 0; j < 8; ++j) bx[j] = (_Float16)0.f;
                if (quad == 0) {
                    const float* xp = xs + t * 12 + (lane & 3);
                    bx[0] = (_Float16)xp[0];
                    bx[1] = (_Float16)xp[4];
                    bx[2] = (_Float16)xp[8];
                }
                const _Float16* hsrc = h1T[(t + 1) & 1];
                const f16x8 bh0 = *(const f16x8*)(hsrc + n * HP + quad * 8);
                const f16x8 bh1 = *(const f16x8*)(hsrc + n * HP + quad * 8 + 32);
                f32x4 acc[4];
                #pragma unroll
                for (int g_ = 0; g_ < 4; ++g_) {
                    f32x4 a = __builtin_amdgcn_mfma_f32_16x16x32_f16(axf[g_], bx, biasf[g_], 0, 0, 0);
                    a = __builtin_amdgcn_mfma_f32_16x16x32_f16(whh[g_][0], bh0, a, 0, 0, 0);
                    a = __builtin_amdgcn_mfma_f32_16x16x32_f16(whh[g_][1], bh1, a, 0, 0, 0);
                    acc[g_] = a;
                }
                if (n < 4) {
                    #pragma unroll
                    for (int r = 0; r < 4; ++r) {
                        const int slot = (16 * quad + 4 * r + n) ^ (quad << 2);
                        f32x4 v = {acc[0][r], acc[1][r], acc[2][r], acc[3][r]};
                        cellA[w][slot] = v;
                    }
                }
                const f32x4 gate = cellA[w][rdslot];
                const float is = sigmoidf_(gate[0]);
                const float fs = sigmoidf_(gate[1]);
                const float gt = tanhf_(gate[2]);
                const float os = sigmoidf_(gate[3]);
                creg = fs * creg + is * gt;
                h1T[t & 1][cb * HP + 16 * w + cu] = (_Float16)(os * tanhf_(creg));
            }
        } else {
            if (t >= 1) {
                // fused K=128 matvec over [h1(t-1); h2(t-2)]
                const _Float16* h1src = h1T[(t + 1) & 1];
                const _Float16* h2src = h2T[(t + 1) & 1];
                const f16x8 b10 = *(const f16x8*)(h1src + n * HP + quad * 8);
                const f16x8 b11 = *(const f16x8*)(h1src + n * HP + quad * 8 + 32);
                const f16x8 b20 = *(const f16x8*)(h2src + n * HP + quad * 8);
                const f16x8 b21 = *(const f16x8*)(h2src + n * HP + quad * 8 + 32);
                f32x4 acc[4];
                #pragma unroll
                for (int g_ = 0; g_ < 4; ++g_) {
                    f32x4 a = __builtin_amdgcn_mfma_f32_16x16x32_f16(wih[g_][0], b10, biasf[g_], 0, 0, 0);
                    a = __builtin_amdgcn_mfma_f32_16x16x32_f16(wih[g_][1], b11, a, 0, 0, 0);
                    a = __builtin_amdgcn_mfma_f32_16x16x32_f16(whh[g_][0], b20, a, 0, 0, 0);
                    a = __builtin_amdgcn_mfma_f32_16x16x32_f16(whh[g_][1], b21, a, 0, 0, 0);
                    acc[g_] = a;
                }
                if (n < 4) {
                    #pragma unroll
                    for (int r = 0; r < 4; ++r) {
                        const int slot = (16 * quad + 4 * r + n) ^ (quad << 2);
                        f32x4 v = {acc[0][r], acc[1][r], acc[2][r], acc[3][r]};
                        cellC[w][slot] = v;
                    }
                }
                const f32x4 gate = cellC[w][rdslot];
                const float is = sigmoidf_(gate[0]);
                const float fs = sigmoidf_(gate[1]);
                const float gt = tanhf_(gate[2]);
                const float os = sigmoidf_(gate[3]);
                creg = fs * creg + is * gt;
                const float h = os * tanhf_(creg);
                h2T[t & 1][cb * HP + 16 * w + cu] = (_Float16)h;   // h2(t-1)
                if (t == TT) h2f[cb * 68 + 16 * w + cu] = h;       // h2(TT-1) fp32
            }
        }
        __syncthreads();
    }

    // ---- epilogue: logits + softmax on fp32 h2 ----
    if (tid < 16) {
        const int b = tid & 3, o = tid >> 2;
        float acc = b_out[o];
        #pragma unroll
        for (int j = 0; j < HH; ++j)
            acc = fmaf(w_out[o * HH + j], h2f[b * 68 + j], acc);
        lg[b][o] = acc;
    }
    __syncthreads();
    if (tid < NB) {
        const int b = tid;
        const float l0 = lg[b][0], l1 = lg[b][1], l2 = lg[b][2], l3 = lg[b][3];
        const float m  = fmaxf(fmaxf(l0, l1), fmaxf(l2, l3));
        const float e0 = __expf(l0 - m), e1 = __expf(l1 - m);
        const float e2 = __expf(l2 - m), e3 = __expf(l3 - m);
        const float sum = 1.0f / (e0 + e1 + e2 + e3);
        out[(b0 + b) * 4 + 0] = e0 * sum;
        out[(b0 + b) * 4 + 1] = e1 * sum;
        out[(b0 + b) * 4 + 2] = e2 * sum;
        out[(b0 + b) * 4 + 3] = e3 * sum;
    }
}

extern "C" void kernel_launch(void* const* d_in, const int* in_sizes, int n_in,
                              void* d_out, int out_size, void* d_ws, size_t ws_size,
                              hipStream_t stream) {
    const float* x     = (const float*)d_in[0];
    const float* w_ih0 = (const float*)d_in[1];
    const float* w_hh0 = (const float*)d_in[2];
    const float* b_ih0 = (const float*)d_in[3];
    const float* b_hh0 = (const float*)d_in[4];
    const float* w_ih1 = (const float*)d_in[5];
    const float* w_hh1 = (const float*)d_in[6];
    const float* b_ih1 = (const float*)d_in[7];
    const float* b_hh1 = (const float*)d_in[8];
    const float* w_out = (const float*)d_in[9];
    const float* b_out = (const float*)d_in[10];
    float* out = (float*)d_out;

    hipLaunchKernelGGL(lstm_mfma, dim3(NBLK), dim3(512), 0, stream,
                       x, w_ih0, w_hh0, b_ih0, b_hh0,
                       w_ih1, w_hh1, b_ih1, b_hh1,
                       w_out, b_out, out);
}